// Round 2
// baseline (154131.824 us; speedup 1.0000x reference)
//
#include <hip/hip_runtime.h>
#include <hip/hip_cooperative_groups.h>
#include <cstdint>
#include <cstddef>

namespace cg = cooperative_groups;

#define T_STEPS 1000
#define B_SZ    128
#define F_IN    72
#define NU      512
#define NC      14
#define K0TOT   592   /* 80 (x padded 72->80) + 512 (h0) */
#define K1TOT   1024  /* 512 (h0n via G1) + 512 (h1 via U1) */

// ---- workspace layout (float offsets) ----
#define OFF_BP0   0
#define SZ_BP0    (128*K0TOT*16)
#define OFF_BP1   (OFF_BP0 + SZ_BP0)
#define SZ_BP1    (128*K1TOT*16)
#define OFF_S1P   (OFF_BP1 + SZ_BP1)
#define OFF_ZB1P  (OFF_S1P + 2048)
#define OFF_B0P   (OFF_ZB1P + 2048)
#define OFF_STATE (OFF_B0P + 2048)      /* h0buf[2], c0, h1, c1 : 5*65536 */
#define OFF_MU    (OFF_STATE + 5*65536)
#define OFF_RSTD  (OFF_MU + 128)

// ---------------- weight packing ----------------
// Bp0[ntile][k 0..591][16]; c = u*4+g ; zcol = ntile*4 + u + 512*g
__global__ void pack0_kernel(const float* __restrict__ w0, const float* __restrict__ u0,
                             float* __restrict__ bp0)
{
    int blk = blockIdx.x;            // 128 ntiles * 10 kchunks
    int ntile = blk / 10, kc = blk % 10;
    int k0 = kc * 64;
#pragma unroll
    for (int p = 0; p < 4; p++) {
        int e = threadIdx.x + p * 256;
        int kr = e >> 4, c = e & 15;
        int k = k0 + kr;
        if (k < K0TOT) {
            int u = c >> 2, g = c & 3;
            int zcol = ntile * 4 + u + 512 * g;
            float v;
            if (k < F_IN)      v = w0[k * 2048 + zcol];
            else if (k < 80)   v = 0.f;
            else               v = u0[(k - 80) * 2048 + zcol];
            bp0[((size_t)ntile * K0TOT + k) * 16 + c] = v;
        }
    }
}

// Bp1[ntile][k 0..1023][16]: k<512 -> gamma[k]*W1[k][zcol], else U1[k-512][zcol]
__global__ void pack1_kernel(const float* __restrict__ w1, const float* __restrict__ u1,
                             const float* __restrict__ gamma, float* __restrict__ bp1)
{
    int blk = blockIdx.x;            // 128 * 16
    int ntile = blk >> 4, kc = blk & 15;
    int k0 = kc * 64;
#pragma unroll
    for (int p = 0; p < 4; p++) {
        int e = threadIdx.x + p * 256;
        int kr = e >> 4, c = e & 15;
        int k = k0 + kr;
        int u = c >> 2, g = c & 3;
        int zcol = ntile * 4 + u + 512 * g;
        float v = (k < NU) ? gamma[k] * w1[k * 2048 + zcol]
                           : u1[(k - NU) * 2048 + zcol];
        bp1[((size_t)ntile * K1TOT + k) * 16 + c] = v;
    }
}

// s1p[pc] = sum_k gamma[k]*W1[k][zcol]; zb1p[pc] = b1 + sum_k beta[k]*W1[k][zcol]; b0p packed
__global__ void sums_kernel(const float* __restrict__ w1, const float* __restrict__ gamma,
                            const float* __restrict__ beta, const float* __restrict__ b0,
                            const float* __restrict__ b1,
                            float* __restrict__ s1p, float* __restrict__ zb1p,
                            float* __restrict__ b0p)
{
    int zcol = blockIdx.x * 256 + threadIdx.x;   // 8 blocks * 256
    float gs = 0.f, bs = 0.f;
    for (int k = 0; k < NU; k++) {
        float w = w1[k * 2048 + zcol];
        gs += gamma[k] * w;
        bs += beta[k] * w;
    }
    int g = zcol >> 9, r = zcol & 511, nt = r >> 2, u = r & 3;
    int pc = nt * 16 + u * 4 + g;
    s1p[pc]  = gs;
    zb1p[pc] = b1[zcol] + bs;
    b0p[pc]  = b0[zcol];
}

// ---------------- main persistent kernel ----------------
__device__ __forceinline__ float sigf(float x)     { return 1.f / (1.f + __expf(-x)); }
__device__ __forceinline__ float tanhfast(float x) { return 2.f / (1.f + __expf(-2.f * x)) - 1.f; }

template <int KC>
__device__ __forceinline__ void gemm_chunk(const float* __restrict__ SM, int abase, int bl,
                                           const float* __restrict__ bp, float acc[8])
{
#pragma unroll
    for (int k = 0; k < KC; k++) {
        float a = SM[abase + k * 65 + bl];
        float4 b0 = *(const float4*)(bp + k * 16);
        float4 b1 = *(const float4*)(bp + k * 16 + 4);
        acc[0] = fmaf(a, b0.x, acc[0]); acc[1] = fmaf(a, b0.y, acc[1]);
        acc[2] = fmaf(a, b0.z, acc[2]); acc[3] = fmaf(a, b0.w, acc[3]);
        acc[4] = fmaf(a, b1.x, acc[4]); acc[5] = fmaf(a, b1.y, acc[5]);
        acc[6] = fmaf(a, b1.z, acc[6]); acc[7] = fmaf(a, b1.w, acc[7]);
    }
}

// stage 64 rows x KC cols of src (row stride given) into SM transposed [k][row], stride 65
template <int KC>
__device__ __forceinline__ void stage_chunk(float* __restrict__ SM, int abase, int gtid,
                                            const float* __restrict__ src, int rowstride)
{
#pragma unroll
    for (int i = 0; i < (64 * KC) / 128; i++) {
        int e = gtid + i * 128;
        int row = e / KC;
        int kk = e - row * KC;
        SM[abase + kk * 65 + row] = src[row * rowstride + kk];
    }
}

__device__ __forceinline__ void stage_x(float* __restrict__ SM, int abase, int gtid,
                                        const float* __restrict__ src, int ks)
{
#pragma unroll
    for (int i = 0; i < 10; i++) {
        int e = gtid + i * 128;
        int row = e / 20;
        int kk = e - row * 20;
        int kg = ks * 20 + kk;
        float v = (kg < F_IN) ? src[row * 72000 + kg] : 0.f;
        SM[abase + kk * 65 + row] = v;
    }
}

__device__ void ypass(const float* __restrict__ h1, const float* __restrict__ wf,
                      const float* __restrict__ bf, float* __restrict__ out,
                      int b, int tw, int lane)
{
    const float* hr = h1 + b * NU;
    float hv[8];
#pragma unroll
    for (int i = 0; i < 8; i++) hv[i] = hr[lane * 8 + i];
    float z[NC];
#pragma unroll
    for (int c = 0; c < NC; c++) {
        float a = 0.f;
#pragma unroll
        for (int i = 0; i < 8; i++) a = fmaf(hv[i], wf[(lane * 8 + i) * NC + c], a);
        z[c] = a;
    }
#pragma unroll
    for (int off = 32; off > 0; off >>= 1) {
#pragma unroll
        for (int c = 0; c < NC; c++) z[c] += __shfl_xor(z[c], off);
    }
    if (lane == 0) {
        float m = -1e30f;
#pragma unroll
        for (int c = 0; c < NC; c++) { z[c] += bf[c]; m = fmaxf(m, z[c]); }
        float s = 0.f, e[NC];
#pragma unroll
        for (int c = 0; c < NC; c++) { e[c] = __expf(z[c] - m); s += e[c]; }
        float inv = 1.f / s;
        float* o = out + ((size_t)b * T_STEPS + tw) * NC;
#pragma unroll
        for (int c = 0; c < NC; c++) o[c] = e[c] * inv;
    }
}

__global__ __launch_bounds__(512, 1)
void lstm_main(const float* __restrict__ x,
               const float* __restrict__ wf, const float* __restrict__ bf,
               float* __restrict__ ws, float* __restrict__ out)
{
    cg::grid_group grid = cg::this_grid();
    __shared__ float SM[8320];   // 4 groups x [32][65] A-tiles; reused as zex after K-loops

    const float* __restrict__ bp0  = ws + OFF_BP0;
    const float* __restrict__ bp1  = ws + OFF_BP1;
    const float* __restrict__ s1p  = ws + OFF_S1P;
    const float* __restrict__ zb1p = ws + OFF_ZB1P;
    const float* __restrict__ b0p  = ws + OFF_B0P;
    float* __restrict__ state = ws + OFF_STATE;
    float* __restrict__ h0buf = state;               // 2*65536
    float* __restrict__ c0    = state + 2 * 65536;
    float* __restrict__ h1    = state + 3 * 65536;
    float* __restrict__ c1    = state + 4 * 65536;
    float* __restrict__ muv   = ws + OFF_MU;
    float* __restrict__ rsv   = ws + OFF_RSTD;

    const int tid  = threadIdx.x;
    const int bl   = tid & 63;             // batch row within tile
    const int ks   = (tid >> 6) & 3;       // K-split group
    const int ch   = tid >> 8;             // column half (8 cols each)
    const int gtid = bl + ((tid >> 8) << 6);  // 0..127 within ks-group
    const int abase = ks * 2080;           // 32*65 per group
    const int blk = blockIdx.x;
    const int mtile = blk & 1, ntile = blk >> 1;
    const int rb = mtile * 64;

    // zero recurrent state (ws is poisoned before timing; must re-init every launch)
    for (int i = blk * 512 + tid; i < 5 * 65536; i += 256 * 512) state[i] = 0.f;
    grid.sync();

#pragma unroll 1
    for (int t = 0; t < T_STEPS; t++) {
        float* __restrict__ h0cur = h0buf + (t & 1) * 65536;
        const float* __restrict__ h0prev = h0buf + ((t & 1) ^ 1) * 65536;

        // ================= PHASE A: z0 = [x_t | h0] @ [W0;U0] -> h0cur, c0 ===========
        float acc[8] = {0.f, 0.f, 0.f, 0.f, 0.f, 0.f, 0.f, 0.f};
        const float* bpA = bp0 + ((size_t)ntile * K0TOT) * 16 + ch * 8;

        stage_x(SM, abase, gtid, x + (size_t)rb * 72000 + t * 72, ks);
        __syncthreads();
        gemm_chunk<20>(SM, abase, bl, bpA + (ks * 20) * 16, acc);
        __syncthreads();
#pragma unroll 1
        for (int cc = 0; cc < 4; cc++) {
            stage_chunk<32>(SM, abase, gtid, h0prev + rb * NU + ks * 128 + cc * 32, NU);
            __syncthreads();
            gemm_chunk<32>(SM, abase, bl, bpA + (80 + ks * 128 + cc * 32) * 16, acc);
            __syncthreads();
        }
#pragma unroll
        for (int i = 0; i < 8; i++) SM[ks * 1024 + (ch * 8 + i) * 64 + bl] = acc[i];
        __syncthreads();
        if (tid < 256) {
            int b = tid & 63, u = tid >> 6;
            int pcb = ntile * 16 + u * 4;
            float z[4];
#pragma unroll
            for (int g = 0; g < 4; g++) {
                int c = u * 4 + g;
                z[g] = SM[c * 64 + b] + SM[1024 + c * 64 + b] + SM[2048 + c * 64 + b] +
                       SM[3072 + c * 64 + b] + b0p[pcb + g];
            }
            int gb = rb + b, j = ntile * 4 + u, idx = gb * NU + j;
            float ig = sigf(z[0]), fg = sigf(z[1]), gg = tanhfast(z[2]), og = sigf(z[3]);
            float cn = fg * c0[idx] + ig * gg;
            c0[idx] = cn;
            h0cur[idx] = og * tanhfast(cn);
        }
        grid.sync();   // -------- SYNC 1: h0cur visible everywhere --------

        // LN stats (blocks 0..127, wave 0), in parallel with phase-B staging elsewhere
        if (blk < 128 && tid < 64) {
            const float* hr = h0cur + blk * NU;
            float s = 0.f, q = 0.f;
#pragma unroll
            for (int i = 0; i < 8; i++) { float v = hr[tid * 8 + i]; s += v; q += v * v; }
#pragma unroll
            for (int off = 32; off > 0; off >>= 1) { s += __shfl_xor(s, off); q += __shfl_xor(q, off); }
            if (tid == 0) {
                float m = s * (1.f / 512.f);
                float var = q * (1.f / 512.f) - m * m;
                muv[blk] = m;
                rsv[blk] = rsqrtf(var + 1e-3f);
            }
        }
        // softmax head for step t-1 (blocks 128..255, wave 0) — h1 still holds h1(t-1)
        if (blk >= 128 && tid < 64 && t > 0) {
            ypass(h1, wf, bf, out, blk - 128, t - 1, tid);
        }

        // ============ PHASE B: z1 = h0n@G1 + h1@U1 (LN folded to epilogue) ==========
        float accG[8] = {0.f, 0.f, 0.f, 0.f, 0.f, 0.f, 0.f, 0.f};
        float accU[8] = {0.f, 0.f, 0.f, 0.f, 0.f, 0.f, 0.f, 0.f};
        const float* bpB = bp1 + ((size_t)ntile * K1TOT) * 16 + ch * 8;
#pragma unroll 1
        for (int cc = 0; cc < 4; cc++) {
            stage_chunk<32>(SM, abase, gtid, h0cur + rb * NU + ks * 128 + cc * 32, NU);
            __syncthreads();
            gemm_chunk<32>(SM, abase, bl, bpB + (ks * 128 + cc * 32) * 16, accG);
            __syncthreads();
        }
#pragma unroll 1
        for (int cc = 0; cc < 4; cc++) {
            stage_chunk<32>(SM, abase, gtid, h1 + rb * NU + ks * 128 + cc * 32, NU);
            __syncthreads();
            gemm_chunk<32>(SM, abase, bl, bpB + (512 + ks * 128 + cc * 32) * 16, accU);
            __syncthreads();
        }
#pragma unroll
        for (int i = 0; i < 8; i++) {
            SM[ks * 1024 + (ch * 8 + i) * 64 + bl]        = accG[i];
            SM[4096 + ks * 1024 + (ch * 8 + i) * 64 + bl] = accU[i];
        }
        __syncthreads();
        grid.sync();   // -------- SYNC 2: mu/rstd visible; all h0/h1 reads done --------
        if (tid < 256) {
            int b = tid & 63, u = tid >> 6;
            int gb = rb + b;
            float rs = rsv[gb], m = muv[gb];
            int pcb = ntile * 16 + u * 4;
            float z[4];
#pragma unroll
            for (int g = 0; g < 4; g++) {
                int c = u * 4 + g;
                float zG = SM[c * 64 + b] + SM[1024 + c * 64 + b] + SM[2048 + c * 64 + b] + SM[3072 + c * 64 + b];
                float zU = SM[4096 + c * 64 + b] + SM[5120 + c * 64 + b] + SM[6144 + c * 64 + b] + SM[7168 + c * 64 + b];
                z[g] = rs * (zG - m * s1p[pcb + g]) + zb1p[pcb + g] + zU;
            }
            float ig = sigf(z[0]), fg = sigf(z[1]), gg = tanhfast(z[2]), og = sigf(z[3]);
            int j = ntile * 4 + u, idx = gb * NU + j;
            float cn = fg * c1[idx] + ig * gg;
            c1[idx] = cn;
            h1[idx] = og * tanhfast(cn);
        }
        __syncthreads();  // protect SM (zex) from next iteration's staging writes
    }

    grid.sync();
    if (blk >= 128 && tid < 64) {
        ypass(h1, wf, bf, out, blk - 128, T_STEPS - 1, tid);
    }
}

// ---------------- launcher ----------------
extern "C" void kernel_launch(void* const* d_in, const int* in_sizes, int n_in,
                              void* d_out, int out_size, void* d_ws, size_t ws_size,
                              hipStream_t stream)
{
    const float* x     = (const float*)d_in[0];
    const float* w0    = (const float*)d_in[1];
    const float* u0    = (const float*)d_in[2];
    const float* b0    = (const float*)d_in[3];
    const float* gamma = (const float*)d_in[4];
    const float* beta  = (const float*)d_in[5];
    const float* w1    = (const float*)d_in[6];
    const float* u1    = (const float*)d_in[7];
    const float* b1    = (const float*)d_in[8];
    const float* wf    = (const float*)d_in[9];
    const float* bf    = (const float*)d_in[10];
    float* out = (float*)d_out;
    float* ws  = (float*)d_ws;

    hipLaunchKernelGGL(pack0_kernel, dim3(128 * 10), dim3(256), 0, stream, w0, u0, ws + OFF_BP0);
    hipLaunchKernelGGL(pack1_kernel, dim3(128 * 16), dim3(256), 0, stream, w1, u1, gamma, ws + OFF_BP1);
    hipLaunchKernelGGL(sums_kernel, dim3(8), dim3(256), 0, stream,
                       w1, gamma, beta, b0, b1, ws + OFF_S1P, ws + OFF_ZB1P, ws + OFF_B0P);

    float* outp = out;
    float* wsp  = ws;
    const float* xp = x;
    const float* wfp = wf;
    const float* bfp = bf;
    void* args[] = { (void*)&xp, (void*)&wfp, (void*)&bfp, (void*)&wsp, (void*)&outp };
    hipLaunchCooperativeKernel((void*)lstm_main, dim3(256), dim3(512), args, 0, stream);
}

// Round 3
// 153708.813 us; speedup vs baseline: 1.0028x; 1.0028x over previous
//
#include <hip/hip_runtime.h>
#include <hip/hip_cooperative_groups.h>
#include <cstdint>
#include <cstddef>

namespace cg = cooperative_groups;

#define T_STEPS 1000
#define B_SZ    128
#define F_IN    72
#define NU      512
#define NC      14
#define K0TOT   592   /* 80 (x padded 72->80) + 512 (h0) */
#define K1TOT   1024  /* 512 (h0n via G1) + 512 (h1 via U1) */

// ---- workspace layout (float offsets) ----
#define OFF_BP0   0
#define SZ_BP0    (128*K0TOT*16)
#define OFF_BP1   (OFF_BP0 + SZ_BP0)
#define SZ_BP1    (128*K1TOT*16)
#define OFF_S1P   (OFF_BP1 + SZ_BP1)
#define OFF_ZB1P  (OFF_S1P + 2048)
#define OFF_B0P   (OFF_ZB1P + 2048)
#define OFF_STATE (OFF_B0P + 2048)      /* h0buf[2], c0, h1, c1 : 5*65536 */
#define OFF_MU    (OFF_STATE + 5*65536)
#define OFF_RSTD  (OFF_MU + 128)

// ---------------- weight packing ----------------
// Bp0[ntile][k 0..591][16]; c = u*4+g ; zcol = ntile*4 + u + 512*g
__global__ void pack0_kernel(const float* __restrict__ w0, const float* __restrict__ u0,
                             float* __restrict__ bp0)
{
    int blk = blockIdx.x;            // 128 ntiles * 10 kchunks
    int ntile = blk / 10, kc = blk % 10;
    int k0 = kc * 64;
#pragma unroll
    for (int p = 0; p < 4; p++) {
        int e = threadIdx.x + p * 256;
        int kr = e >> 4, c = e & 15;
        int k = k0 + kr;
        if (k < K0TOT) {
            int u = c >> 2, g = c & 3;
            int zcol = ntile * 4 + u + 512 * g;
            float v;
            if (k < F_IN)      v = w0[k * 2048 + zcol];
            else if (k < 80)   v = 0.f;
            else               v = u0[(k - 80) * 2048 + zcol];
            bp0[((size_t)ntile * K0TOT + k) * 16 + c] = v;
        }
    }
}

// Bp1[ntile][k 0..1023][16]: k<512 -> gamma[k]*W1[k][zcol], else U1[k-512][zcol]
__global__ void pack1_kernel(const float* __restrict__ w1, const float* __restrict__ u1,
                             const float* __restrict__ gamma, float* __restrict__ bp1)
{
    int blk = blockIdx.x;            // 128 * 16
    int ntile = blk >> 4, kc = blk & 15;
    int k0 = kc * 64;
#pragma unroll
    for (int p = 0; p < 4; p++) {
        int e = threadIdx.x + p * 256;
        int kr = e >> 4, c = e & 15;
        int k = k0 + kr;
        int u = c >> 2, g = c & 3;
        int zcol = ntile * 4 + u + 512 * g;
        float v = (k < NU) ? gamma[k] * w1[k * 2048 + zcol]
                           : u1[(k - NU) * 2048 + zcol];
        bp1[((size_t)ntile * K1TOT + k) * 16 + c] = v;
    }
}

// s1p[pc] = sum_k gamma[k]*W1[k][zcol]; zb1p[pc] = b1 + sum_k beta[k]*W1[k][zcol]; b0p packed
__global__ void sums_kernel(const float* __restrict__ w1, const float* __restrict__ gamma,
                            const float* __restrict__ beta, const float* __restrict__ b0,
                            const float* __restrict__ b1,
                            float* __restrict__ s1p, float* __restrict__ zb1p,
                            float* __restrict__ b0p)
{
    int zcol = blockIdx.x * 256 + threadIdx.x;   // 8 blocks * 256
    float gs = 0.f, bs = 0.f;
    for (int k = 0; k < NU; k++) {
        float w = w1[k * 2048 + zcol];
        gs += gamma[k] * w;
        bs += beta[k] * w;
    }
    int g = zcol >> 9, r = zcol & 511, nt = r >> 2, u = r & 3;
    int pc = nt * 16 + u * 4 + g;
    s1p[pc]  = gs;
    zb1p[pc] = b1[zcol] + bs;
    b0p[pc]  = b0[zcol];
}

// ---------------- main persistent kernel ----------------
__device__ __forceinline__ float sigf(float x)     { return 1.f / (1.f + __expf(-x)); }
__device__ __forceinline__ float tanhfast(float x) { return 2.f / (1.f + __expf(-2.f * x)) - 1.f; }

template <int KC>
__device__ __forceinline__ void gemm_chunk(const float* __restrict__ SM, int abase, int bl,
                                           const float* __restrict__ bp, float acc[8])
{
#pragma unroll
    for (int k = 0; k < KC; k++) {
        float a = SM[abase + k * 65 + bl];
        float4 b0 = *(const float4*)(bp + k * 16);
        float4 b1 = *(const float4*)(bp + k * 16 + 4);
        acc[0] = fmaf(a, b0.x, acc[0]); acc[1] = fmaf(a, b0.y, acc[1]);
        acc[2] = fmaf(a, b0.z, acc[2]); acc[3] = fmaf(a, b0.w, acc[3]);
        acc[4] = fmaf(a, b1.x, acc[4]); acc[5] = fmaf(a, b1.y, acc[5]);
        acc[6] = fmaf(a, b1.z, acc[6]); acc[7] = fmaf(a, b1.w, acc[7]);
    }
}

// stage 64 rows x KC cols of src (row stride given) into SM transposed [k][row], stride 65
template <int KC>
__device__ __forceinline__ void stage_chunk(float* __restrict__ SM, int abase, int gtid,
                                            const float* __restrict__ src, int rowstride)
{
#pragma unroll
    for (int i = 0; i < (64 * KC) / 128; i++) {
        int e = gtid + i * 128;
        int row = e / KC;
        int kk = e - row * KC;
        SM[abase + kk * 65 + row] = src[row * rowstride + kk];
    }
}

__device__ __forceinline__ void stage_x(float* __restrict__ SM, int abase, int gtid,
                                        const float* __restrict__ src, int ks)
{
#pragma unroll
    for (int i = 0; i < 10; i++) {
        int e = gtid + i * 128;
        int row = e / 20;
        int kk = e - row * 20;
        int kg = ks * 20 + kk;
        float v = (kg < F_IN) ? src[row * 72000 + kg] : 0.f;
        SM[abase + kk * 65 + row] = v;
    }
}

__device__ void ypass(const float* __restrict__ h1, const float* __restrict__ wf,
                      const float* __restrict__ bf, float* __restrict__ out,
                      int b, int tw, int lane)
{
    const float* hr = h1 + b * NU;
    float hv[8];
#pragma unroll
    for (int i = 0; i < 8; i++) hv[i] = hr[lane * 8 + i];
    float z[NC];
#pragma unroll
    for (int c = 0; c < NC; c++) {
        float a = 0.f;
#pragma unroll
        for (int i = 0; i < 8; i++) a = fmaf(hv[i], wf[(lane * 8 + i) * NC + c], a);
        z[c] = a;
    }
#pragma unroll
    for (int off = 32; off > 0; off >>= 1) {
#pragma unroll
        for (int c = 0; c < NC; c++) z[c] += __shfl_xor(z[c], off);
    }
    if (lane == 0) {
        float m = -1e30f;
#pragma unroll
        for (int c = 0; c < NC; c++) { z[c] += bf[c]; m = fmaxf(m, z[c]); }
        float s = 0.f, e[NC];
#pragma unroll
        for (int c = 0; c < NC; c++) { e[c] = __expf(z[c] - m); s += e[c]; }
        float inv = 1.f / s;
        float* o = out + ((size_t)b * T_STEPS + tw) * NC;
#pragma unroll
        for (int c = 0; c < NC; c++) o[c] = e[c] * inv;
    }
}

__global__ __launch_bounds__(512, 1)
void lstm_main(const float* __restrict__ x,
               const float* __restrict__ wf, const float* __restrict__ bf,
               float* __restrict__ ws, float* __restrict__ out)
{
    cg::grid_group grid = cg::this_grid();
    __shared__ float SM[8320];   // 4 groups x [32][65] A-tiles; reused as zex after K-loops

    const float* __restrict__ bp0  = ws + OFF_BP0;
    const float* __restrict__ bp1  = ws + OFF_BP1;
    const float* __restrict__ s1p  = ws + OFF_S1P;
    const float* __restrict__ zb1p = ws + OFF_ZB1P;
    const float* __restrict__ b0p  = ws + OFF_B0P;
    float* __restrict__ state = ws + OFF_STATE;
    float* __restrict__ h0buf = state;               // 2*65536
    float* __restrict__ c0    = state + 2 * 65536;
    float* __restrict__ h1    = state + 3 * 65536;
    float* __restrict__ c1    = state + 4 * 65536;
    float* __restrict__ muv   = ws + OFF_MU;
    float* __restrict__ rsv   = ws + OFF_RSTD;

    const int tid  = threadIdx.x;
    const int bl   = tid & 63;             // batch row within tile
    const int ks   = (tid >> 6) & 3;       // K-split group
    const int ch   = tid >> 8;             // column half (8 cols each)
    const int gtid = bl + ((tid >> 8) << 6);  // 0..127 within ks-group
    const int abase = ks * 2080;           // 32*65 per group
    const int blk = blockIdx.x;
    const int mtile = blk & 1, ntile = blk >> 1;
    const int rb = mtile * 64;

    // zero recurrent state (ws is poisoned before timing; must re-init every launch)
    for (int i = blk * 512 + tid; i < 5 * 65536; i += 256 * 512) state[i] = 0.f;
    grid.sync();

#pragma unroll 1
    for (int t = 0; t < T_STEPS; t++) {
        float* __restrict__ h0cur = h0buf + (t & 1) * 65536;
        const float* __restrict__ h0prev = h0buf + ((t & 1) ^ 1) * 65536;

        // ================= PHASE A: z0 = [x_t | h0] @ [W0;U0] -> h0cur, c0 ===========
        float acc[8] = {0.f, 0.f, 0.f, 0.f, 0.f, 0.f, 0.f, 0.f};
        const float* bpA = bp0 + ((size_t)ntile * K0TOT) * 16 + ch * 8;

        stage_x(SM, abase, gtid, x + (size_t)rb * 72000 + t * 72, ks);
        __syncthreads();
        gemm_chunk<20>(SM, abase, bl, bpA + (ks * 20) * 16, acc);
        __syncthreads();
#pragma unroll 1
        for (int cc = 0; cc < 4; cc++) {
            stage_chunk<32>(SM, abase, gtid, h0prev + rb * NU + ks * 128 + cc * 32, NU);
            __syncthreads();
            gemm_chunk<32>(SM, abase, bl, bpA + (80 + ks * 128 + cc * 32) * 16, acc);
            __syncthreads();
        }
#pragma unroll
        for (int i = 0; i < 8; i++) SM[ks * 1024 + (ch * 8 + i) * 64 + bl] = acc[i];
        __syncthreads();
        if (tid < 256) {
            int b = tid & 63, u = tid >> 6;
            int pcb = ntile * 16 + u * 4;
            float z[4];
#pragma unroll
            for (int g = 0; g < 4; g++) {
                int c = u * 4 + g;
                z[g] = SM[c * 64 + b] + SM[1024 + c * 64 + b] + SM[2048 + c * 64 + b] +
                       SM[3072 + c * 64 + b] + b0p[pcb + g];
            }
            int gb = rb + b, j = ntile * 4 + u, idx = gb * NU + j;
            float ig = sigf(z[0]), fg = sigf(z[1]), gg = tanhfast(z[2]), og = sigf(z[3]);
            float cn = fg * c0[idx] + ig * gg;
            c0[idx] = cn;
            h0cur[idx] = og * tanhfast(cn);
        }
        grid.sync();   // -------- SYNC 1: h0cur visible everywhere --------

        // LN stats (blocks 0..127, wave 0), in parallel with phase-B staging elsewhere
        if (blk < 128 && tid < 64) {
            const float* hr = h0cur + blk * NU;
            float s = 0.f, q = 0.f;
#pragma unroll
            for (int i = 0; i < 8; i++) { float v = hr[tid * 8 + i]; s += v; q += v * v; }
#pragma unroll
            for (int off = 32; off > 0; off >>= 1) { s += __shfl_xor(s, off); q += __shfl_xor(q, off); }
            if (tid == 0) {
                float m = s * (1.f / 512.f);
                float var = q * (1.f / 512.f) - m * m;
                muv[blk] = m;
                rsv[blk] = rsqrtf(var + 1e-3f);
            }
        }
        // softmax head for step t-1 (blocks 128..255, wave 0) — h1 still holds h1(t-1)
        if (blk >= 128 && tid < 64 && t > 0) {
            ypass(h1, wf, bf, out, blk - 128, t - 1, tid);
        }

        // ============ PHASE B: z1 = h0n@G1 + h1@U1 (LN folded to epilogue) ==========
        float accG[8] = {0.f, 0.f, 0.f, 0.f, 0.f, 0.f, 0.f, 0.f};
        float accU[8] = {0.f, 0.f, 0.f, 0.f, 0.f, 0.f, 0.f, 0.f};
        const float* bpB = bp1 + ((size_t)ntile * K1TOT) * 16 + ch * 8;
#pragma unroll 1
        for (int cc = 0; cc < 4; cc++) {
            stage_chunk<32>(SM, abase, gtid, h0cur + rb * NU + ks * 128 + cc * 32, NU);
            __syncthreads();
            gemm_chunk<32>(SM, abase, bl, bpB + (ks * 128 + cc * 32) * 16, accG);
            __syncthreads();
        }
#pragma unroll 1
        for (int cc = 0; cc < 4; cc++) {
            stage_chunk<32>(SM, abase, gtid, h1 + rb * NU + ks * 128 + cc * 32, NU);
            __syncthreads();
            gemm_chunk<32>(SM, abase, bl, bpB + (512 + ks * 128 + cc * 32) * 16, accU);
            __syncthreads();
        }
#pragma unroll
        for (int i = 0; i < 8; i++) {
            SM[ks * 1024 + (ch * 8 + i) * 64 + bl]        = accG[i];
            SM[4096 + ks * 1024 + (ch * 8 + i) * 64 + bl] = accU[i];
        }
        __syncthreads();
        grid.sync();   // -------- SYNC 2: mu/rstd visible; all h0/h1 reads done --------
        if (tid < 256) {
            int b = tid & 63, u = tid >> 6;
            int gb = rb + b;
            float rs = rsv[gb], m = muv[gb];
            int pcb = ntile * 16 + u * 4;
            float z[4];
#pragma unroll
            for (int g = 0; g < 4; g++) {
                int c = u * 4 + g;
                float zG = SM[c * 64 + b] + SM[1024 + c * 64 + b] + SM[2048 + c * 64 + b] + SM[3072 + c * 64 + b];
                float zU = SM[4096 + c * 64 + b] + SM[5120 + c * 64 + b] + SM[6144 + c * 64 + b] + SM[7168 + c * 64 + b];
                z[g] = rs * (zG - m * s1p[pcb + g]) + zb1p[pcb + g] + zU;
            }
            float ig = sigf(z[0]), fg = sigf(z[1]), gg = tanhfast(z[2]), og = sigf(z[3]);
            int j = ntile * 4 + u, idx = gb * NU + j;
            float cn = fg * c1[idx] + ig * gg;
            c1[idx] = cn;
            h1[idx] = og * tanhfast(cn);
        }
        __syncthreads();  // protect SM (zex) from next iteration's staging writes
    }

    grid.sync();
    if (blk >= 128 && tid < 64) {
        ypass(h1, wf, bf, out, blk - 128, T_STEPS - 1, tid);
    }
}

// ---------------- launcher ----------------
extern "C" void kernel_launch(void* const* d_in, const int* in_sizes, int n_in,
                              void* d_out, int out_size, void* d_ws, size_t ws_size,
                              hipStream_t stream)
{
    const float* x     = (const float*)d_in[0];
    const float* w0    = (const float*)d_in[1];
    const float* u0    = (const float*)d_in[2];
    const float* b0    = (const float*)d_in[3];
    const float* gamma = (const float*)d_in[4];
    const float* beta  = (const float*)d_in[5];
    const float* w1    = (const float*)d_in[6];
    const float* u1    = (const float*)d_in[7];
    const float* b1    = (const float*)d_in[8];
    const float* wf    = (const float*)d_in[9];
    const float* bf    = (const float*)d_in[10];
    float* out = (float*)d_out;
    float* ws  = (float*)d_ws;

    hipLaunchKernelGGL(pack0_kernel, dim3(128 * 10), dim3(256), 0, stream, w0, u0, ws + OFF_BP0);
    hipLaunchKernelGGL(pack1_kernel, dim3(128 * 16), dim3(256), 0, stream, w1, u1, gamma, ws + OFF_BP1);
    hipLaunchKernelGGL(sums_kernel, dim3(8), dim3(256), 0, stream,
                       w1, gamma, beta, b0, b1, ws + OFF_S1P, ws + OFF_ZB1P, ws + OFF_B0P);

    float* outp = out;
    float* wsp  = ws;
    const float* xp = x;
    const float* wfp = wf;
    const float* bfp = bf;
    void* args[] = { (void*)&xp, (void*)&wfp, (void*)&bfp, (void*)&wsp, (void*)&outp };
    hipLaunchCooperativeKernel((void*)lstm_main, dim3(256), dim3(512), args, 0, stream);
}

// Round 4
// 34307.880 us; speedup vs baseline: 4.4926x; 4.4803x over previous
//
#include <hip/hip_runtime.h>
#include <cstdint>
#include <cstddef>

#define T_STEPS 1000
#define NU      512
#define NC      14
#define K0TOT   592   /* 80 (x padded 72->80) + 512 (h0) */
#define K1TOT   1024  /* 512 (h0n via G1) + 512 (h1 via U1) */

// ---- workspace layout (float offsets) ----
#define OFF_BP0   0
#define SZ_BP0    (128*K0TOT*16)
#define OFF_BP1   (OFF_BP0 + SZ_BP0)
#define SZ_BP1    (128*K1TOT*16)
#define OFF_S1P   (OFF_BP1 + SZ_BP1)
#define OFF_ZB1P  (OFF_S1P + 2048)
#define OFF_B0P   (OFF_ZB1P + 2048)
#define OFF_H0T   (OFF_B0P + 2048)        /* 2 x [512][128] */
#define OFF_H1T   (OFF_H0T + 2*65536)     /* 2 x [512][128] */
#define OFF_H1N   (OFF_H1T + 2*65536)     /* 2 x [128][512] */
#define OFF_WFT   (OFF_H1N + 2*65536)     /* [14][512] */
#define OFF_BAR   (OFF_WFT + 14*512)      /* u32 barrier counter */

// ---------------- weight packing (unchanged layouts) ----------------
// bp0[ntile][k 0..591][16]; c = u*4+g ; zcol = ntile*4 + u + 512*g
__global__ void pack0_kernel(const float* __restrict__ w0, const float* __restrict__ u0,
                             float* __restrict__ bp0)
{
    int blk = blockIdx.x;            // 128 ntiles * 10 kchunks
    int ntile = blk / 10, kc = blk % 10;
    int k0 = kc * 64;
#pragma unroll
    for (int p = 0; p < 4; p++) {
        int e = threadIdx.x + p * 256;
        int kr = e >> 4, c = e & 15;
        int k = k0 + kr;
        if (k < K0TOT) {
            int u = c >> 2, g = c & 3;
            int zcol = ntile * 4 + u + 512 * g;
            float v;
            if (k < 72)        v = w0[k * 2048 + zcol];
            else if (k < 80)   v = 0.f;
            else               v = u0[(k - 80) * 2048 + zcol];
            bp0[((size_t)ntile * K0TOT + k) * 16 + c] = v;
        }
    }
}

__global__ void pack1_kernel(const float* __restrict__ w1, const float* __restrict__ u1,
                             const float* __restrict__ gamma, float* __restrict__ bp1)
{
    int blk = blockIdx.x;            // 128 * 16
    int ntile = blk >> 4, kc = blk & 15;
    int k0 = kc * 64;
#pragma unroll
    for (int p = 0; p < 4; p++) {
        int e = threadIdx.x + p * 256;
        int kr = e >> 4, c = e & 15;
        int k = k0 + kr;
        int u = c >> 2, g = c & 3;
        int zcol = ntile * 4 + u + 512 * g;
        float v = (k < NU) ? gamma[k] * w1[k * 2048 + zcol]
                           : u1[(k - NU) * 2048 + zcol];
        bp1[((size_t)ntile * K1TOT + k) * 16 + c] = v;
    }
}

__global__ void sums_kernel(const float* __restrict__ w1, const float* __restrict__ gamma,
                            const float* __restrict__ beta, const float* __restrict__ b0,
                            const float* __restrict__ b1,
                            float* __restrict__ s1p, float* __restrict__ zb1p,
                            float* __restrict__ b0p)
{
    int zcol = blockIdx.x * 256 + threadIdx.x;   // 8 blocks * 256
    float gs = 0.f, bs = 0.f;
    for (int k = 0; k < NU; k++) {
        float w = w1[k * 2048 + zcol];
        gs += gamma[k] * w;
        bs += beta[k] * w;
    }
    int g = zcol >> 9, r = zcol & 511, nt = r >> 2, u = r & 3;
    int pc = nt * 16 + u * 4 + g;
    s1p[pc]  = gs;
    zb1p[pc] = b1[zcol] + bs;
    b0p[pc]  = b0[zcol];
}

__global__ void wft_kernel(const float* __restrict__ wf, float* __restrict__ wfT)
{
    int i = blockIdx.x * 512 + threadIdx.x;   // 14 blocks * 512
    if (i < NC * NU) {
        int c = i >> 9, u = i & 511;
        wfT[c * NU + u] = wf[u * NC + c];
    }
}

__global__ void init_kernel(float* __restrict__ ws)
{
    size_t i = (size_t)blockIdx.x * 1024 + threadIdx.x;
    if (i < (size_t)6 * 65536) ws[OFF_H0T + i] = 0.f;
    if (i == 0) *((unsigned*)(ws + OFF_BAR)) = 0u;
}

// ---------------- device helpers ----------------
__device__ __forceinline__ float sigf(float x)     { return 1.f / (1.f + __expf(-x)); }
__device__ __forceinline__ float tanhfast(float x) { return 2.f / (1.f + __expf(-2.f * x)) - 1.f; }

__device__ __forceinline__ void fma8(float acc[8], float a, float4 b0, float4 b1)
{
    acc[0] = fmaf(a, b0.x, acc[0]); acc[1] = fmaf(a, b0.y, acc[1]);
    acc[2] = fmaf(a, b0.z, acc[2]); acc[3] = fmaf(a, b0.w, acc[3]);
    acc[4] = fmaf(a, b1.x, acc[4]); acc[5] = fmaf(a, b1.y, acc[5]);
    acc[6] = fmaf(a, b1.z, acc[6]); acc[7] = fmaf(a, b1.w, acc[7]);
}

// butterfly-reduce 4-way K-split (lanes ^16, ^32), write to zex[kw][row 0..63][17]
__device__ __forceinline__ void reduce_zex(float acc[4][8], float* __restrict__ zex,
                                           int kw, int ch, int rg, int ks)
{
#pragma unroll
    for (int r = 0; r < 4; ++r)
#pragma unroll
        for (int c = 0; c < 8; ++c) {
            float v = acc[r][c];
            v += __shfl_xor(v, 16);
            v += __shfl_xor(v, 32);
            acc[r][c] = v;
        }
    const int zb = kw * 1088 + ch * 8;
#pragma unroll
    for (int r = 0; r < 4; ++r) {
        if (ks == r) {
#pragma unroll
            for (int c = 0; c < 8; ++c)
                zex[zb + (rg * 4 + r) * 17 + c] = acc[r][c];
        }
    }
}

// custom grid barrier: monotonic counter, NBLK=256, skew-safe (>= compare)
__device__ __forceinline__ void grid_barrier(unsigned* bar)
{
    __syncthreads();
    if (threadIdx.x == 0) {
        __threadfence();   // release: make our writes device-visible
        unsigned old = __hip_atomic_fetch_add(bar, 1u, __ATOMIC_RELAXED, __HIP_MEMORY_SCOPE_AGENT);
        unsigned target = (old | 255u) + 1u;
        while (__hip_atomic_load(bar, __ATOMIC_RELAXED, __HIP_MEMORY_SCOPE_AGENT) < target)
            __builtin_amdgcn_s_sleep(2);
        __threadfence();   // acquire: invalidate stale cached lines
    }
    __syncthreads();
}

// softmax head for one batch row (64 lanes); h1r = [128][512], wfT = [14][512]
__device__ void ypass(const float* __restrict__ h1r, const float* __restrict__ wfT,
                      const float* __restrict__ bf, float* __restrict__ out,
                      int b, int tw, int lane)
{
    const float* hr = h1r + (size_t)b * NU + lane * 8;
    float4 hA = *(const float4*)hr;
    float4 hB = *(const float4*)(hr + 4);
    float z[NC];
#pragma unroll
    for (int c = 0; c < NC; ++c) {
        const float* wp = wfT + c * NU + lane * 8;
        float4 wA = *(const float4*)wp;
        float4 wB = *(const float4*)(wp + 4);
        float a = hA.x * wA.x;
        a = fmaf(hA.y, wA.y, a); a = fmaf(hA.z, wA.z, a); a = fmaf(hA.w, wA.w, a);
        a = fmaf(hB.x, wB.x, a); a = fmaf(hB.y, wB.y, a);
        a = fmaf(hB.z, wB.z, a); a = fmaf(hB.w, wB.w, a);
        z[c] = a;
    }
#pragma unroll
    for (int off = 32; off > 0; off >>= 1) {
#pragma unroll
        for (int c = 0; c < NC; ++c) z[c] += __shfl_xor(z[c], off);
    }
    if (lane == 0) {
        float m = -1e30f;
#pragma unroll
        for (int c = 0; c < NC; ++c) { z[c] += bf[c]; m = fmaxf(m, z[c]); }
        float s = 0.f, e[NC];
#pragma unroll
        for (int c = 0; c < NC; ++c) { e[c] = __expf(z[c] - m); s += e[c]; }
        float inv = 1.f / s;
        float* o = out + ((size_t)b * T_STEPS + tw) * NC;
#pragma unroll
        for (int c = 0; c < NC; ++c) o[c] = e[c] * inv;
    }
}

// ---------------- main persistent kernel ----------------
// grid 256 = mtile(2) x ntile(128); 512 threads = 8 waves = kw(4) x ch(2)
// lane = rg(16) x ks(4); thread computes 4 rows x 8 cols, K-split 4(ks) x 4(kw)
__global__ __launch_bounds__(512, 2)
void lstm_main(const float* __restrict__ x,
               const float* __restrict__ bf,
               float* __restrict__ ws, float* __restrict__ out)
{
    __shared__ float bpA_lds[K0TOT * 16];   // 37,888 B
    __shared__ float bpB_lds[K1TOT * 16];   // 65,536 B
    __shared__ float xs[64 * 81];           // 20,736 B (x_t transposed-ish, padded)
    __shared__ float zex[4 * 64 * 17];      // 17,408 B (kw partials)
    __shared__ float sq[64 * 17];           //  4,352 B (per-row s,q per wave)

    const float* __restrict__ bp0g = ws + OFF_BP0;
    const float* __restrict__ bp1g = ws + OFF_BP1;
    const float* __restrict__ s1p  = ws + OFF_S1P;
    const float* __restrict__ zb1p = ws + OFF_ZB1P;
    const float* __restrict__ b0p  = ws + OFF_B0P;
    float* __restrict__ h0T = ws + OFF_H0T;
    float* __restrict__ h1T = ws + OFF_H1T;
    float* __restrict__ h1n = ws + OFF_H1N;
    const float* __restrict__ wfT = ws + OFF_WFT;
    unsigned* bar = (unsigned*)(ws + OFF_BAR);

    const int tid  = threadIdx.x;
    const int lane = tid & 63;
    const int w    = tid >> 6;        // wave 0..7
    const int kw   = w >> 1;          // 0..3 K-quarter
    const int ch   = w & 1;           // column half (8 cols)
    const int rg   = lane & 15;       // row group (4 rows each)
    const int ks   = lane >> 4;       // intra-wave K-split 0..3
    const int rg4  = rg * 4;
    const int blk = blockIdx.x;
    const int mtile = blk & 1, ntile = blk >> 1;
    const int rb = mtile * 64;

    // ---- one-time LDS fill: weights + zero xs (incl. zero pad cols 72..80) ----
    {
        const float* s0 = bp0g + (size_t)ntile * (K0TOT * 16);
        for (int i = tid; i < K0TOT * 16; i += 512) bpA_lds[i] = s0[i];
        const float* s1 = bp1g + (size_t)ntile * (K1TOT * 16);
        for (int i = tid; i < K1TOT * 16; i += 512) bpB_lds[i] = s1[i];
        for (int i = tid; i < 64 * 81; i += 512) xs[i] = 0.f;
    }
    __syncthreads();

    // epilogue-thread constants & register c-state (tid<256: b=tid&63, u=(tid>>6)&3)
    const int eb = tid & 63, eu = (tid >> 6) & 3;
    float c0v = 0.f, c1v = 0.f;
    float4 b0v = {0,0,0,0}, s1v = {0,0,0,0}, zbv = {0,0,0,0};
    if (tid < 256) {
        b0v = *(const float4*)&b0p[ntile * 16 + eu * 4];
        s1v = *(const float4*)&s1p[ntile * 16 + eu * 4];
        zbv = *(const float4*)&zb1p[ntile * 16 + eu * 4];
    }
    const float* xrowbase = x + (size_t)rb * 72000;

#pragma unroll 1
    for (int t = 0; t < T_STEPS; ++t) {
        const float* __restrict__ h0prev  = h0T + ((t + 1) & 1) * 65536;
        float* __restrict__       h0cur   = h0T + (t & 1) * 65536;
        const float* __restrict__ h1prev  = h1T + ((t + 1) & 1) * 65536;
        float* __restrict__       h1cur   = h1T + (t & 1) * 65536;
        const float* __restrict__ h1nprev = h1n + ((t + 1) & 1) * 65536;
        float* __restrict__       h1ncur  = h1n + (t & 1) * 65536;

        // ---- stage x_t into LDS (64 rows x 72, transposed access later) ----
        float xr[9];
#pragma unroll
        for (int j = 0; j < 9; ++j) {
            int e = tid + j * 512, row = e / 72, f = e - row * 72;
            xr[j] = xrowbase[(size_t)row * 72000 + t * 72 + f];
        }
#pragma unroll
        for (int j = 0; j < 9; ++j) {
            int e = tid + j * 512, row = e / 72, f = e - row * 72;
            xs[row * 81 + f] = xr[j];
        }
        __syncthreads();

        // ================= PHASE A: z0 = [x_t | h0prev] @ Bp0 =================
        {
            float acc[4][8];
#pragma unroll
            for (int r = 0; r < 4; ++r)
#pragma unroll
                for (int c = 0; c < 8; ++c) acc[r][c] = 0.f;

            if (kw == 0) {
#pragma unroll 4
                for (int i = 0; i < 20; ++i) {          // x part: k = 4i+ks < 80
                    const int k = 4 * i + ks;
                    const float* bp = &bpA_lds[k * 16 + ch * 8];
                    const float4 bA = *(const float4*)bp;
                    const float4 bB = *(const float4*)(bp + 4);
                    fma8(acc[0], xs[(rg4 + 0) * 81 + k], bA, bB);
                    fma8(acc[1], xs[(rg4 + 1) * 81 + k], bA, bB);
                    fma8(acc[2], xs[(rg4 + 2) * 81 + k], bA, bB);
                    fma8(acc[3], xs[(rg4 + 3) * 81 + k], bA, bB);
                }
#pragma unroll 4
                for (int i = 20; i < 37; ++i) {         // h part: k = 80..147
                    const int k = 4 * i + ks;
                    const float4 av = *(const float4*)(h0prev + (size_t)(k - 80) * 128 + rb + rg4);
                    const float* bp = &bpA_lds[k * 16 + ch * 8];
                    const float4 bA = *(const float4*)bp;
                    const float4 bB = *(const float4*)(bp + 4);
                    fma8(acc[0], av.x, bA, bB); fma8(acc[1], av.y, bA, bB);
                    fma8(acc[2], av.z, bA, bB); fma8(acc[3], av.w, bA, bB);
                }
            } else {
                const int kbase = kw * 148;
#pragma unroll 4
                for (int i = 0; i < 37; ++i) {
                    const int k = kbase + 4 * i + ks;
                    const float4 av = *(const float4*)(h0prev + (size_t)(k - 80) * 128 + rb + rg4);
                    const float* bp = &bpA_lds[k * 16 + ch * 8];
                    const float4 bA = *(const float4*)bp;
                    const float4 bB = *(const float4*)(bp + 4);
                    fma8(acc[0], av.x, bA, bB); fma8(acc[1], av.y, bA, bB);
                    fma8(acc[2], av.z, bA, bB); fma8(acc[3], av.w, bA, bB);
                }
            }
            reduce_zex(acc, zex, kw, ch, rg, ks);
        }
        __syncthreads();
        // epilogue A
        if (tid < 256) {
            float z[4];
#pragma unroll
            for (int g = 0; g < 4; ++g) {
                int ci = eb * 17 + eu * 4 + g;
                z[g] = zex[ci] + zex[1088 + ci] + zex[2176 + ci] + zex[3264 + ci];
            }
            z[0] += b0v.x; z[1] += b0v.y; z[2] += b0v.z; z[3] += b0v.w;
            float ig = sigf(z[0]), fg = sigf(z[1]), gg = tanhfast(z[2]), og = sigf(z[3]);
            float cn = fg * c0v + ig * gg;
            c0v = cn;
            h0cur[(ntile * 4 + eu) * 128 + rb + eb] = og * tanhfast(cn);
        }

        grid_barrier(bar);   // ---- the ONE global sync per step ----

        // ---- LN stats (redundant per block, rows rb..rb+63): wave w sums k-slice ----
        {
            float s = 0.f, q = 0.f;
            const float* hp = h0cur + (size_t)(w * 64) * 128 + rb + lane;
#pragma unroll 8
            for (int kk = 0; kk < 64; ++kk) {
                float v = hp[(size_t)kk * 128];
                s += v; q = fmaf(v, v, q);
            }
            sq[lane * 17 + w * 2]     = s;
            sq[lane * 17 + w * 2 + 1] = q;
        }

        // ---- softmax head for step t-1 (blocks 0..127, wave 0) ----
        if (blk < 128 && w == 0 && t > 0) ypass(h1nprev, wfT, bf, out, blk, t - 1, lane);

        // ================= PHASE B: z1 = h0n@G1 + h1prev@U1 (LN folded) ========
        {
            float acc[4][8];
#pragma unroll
            for (int r = 0; r < 4; ++r)
#pragma unroll
                for (int c = 0; c < 8; ++c) acc[r][c] = 0.f;

            const float* __restrict__ Asrc = (kw < 2) ? h0cur : h1prev;
            const int kofs   = (kw & 1) * 256;   // k offset within source
            const int kb_lds = kw * 256;         // k offset within bpB
#pragma unroll 4
            for (int i = 0; i < 64; ++i) {
                const int kk = 4 * i + ks;
                const float4 av = *(const float4*)(Asrc + (size_t)(kofs + kk) * 128 + rb + rg4);
                const float* bp = &bpB_lds[(kb_lds + kk) * 16 + ch * 8];
                const float4 bA = *(const float4*)bp;
                const float4 bB = *(const float4*)(bp + 4);
                fma8(acc[0], av.x, bA, bB); fma8(acc[1], av.y, bA, bB);
                fma8(acc[2], av.z, bA, bB); fma8(acc[3], av.w, bA, bB);
            }
            reduce_zex(acc, zex, kw, ch, rg, ks);
        }
        __syncthreads();
        // epilogue B (applies LN via folded stats)
        if (tid < 256) {
            float s = 0.f, q = 0.f;
#pragma unroll
            for (int w8 = 0; w8 < 8; ++w8) {
                s += sq[eb * 17 + w8 * 2];
                q += sq[eb * 17 + w8 * 2 + 1];
            }
            float m  = s * (1.f / 512.f);
            float rs = rsqrtf(q * (1.f / 512.f) - m * m + 1e-3f);
            float z[4];
#pragma unroll
            for (int g = 0; g < 4; ++g) {
                int ci = eb * 17 + eu * 4 + g;
                float zG = zex[ci] + zex[1088 + ci];
                float zU = zex[2176 + ci] + zex[3264 + ci];
                float s1g = (g == 0) ? s1v.x : (g == 1) ? s1v.y : (g == 2) ? s1v.z : s1v.w;
                float zbg = (g == 0) ? zbv.x : (g == 1) ? zbv.y : (g == 2) ? zbv.z : zbv.w;
                z[g] = rs * (zG - m * s1g) + zU + zbg;
            }
            float ig = sigf(z[0]), fg = sigf(z[1]), gg = tanhfast(z[2]), og = sigf(z[3]);
            float cn = fg * c1v + ig * gg;
            c1v = cn;
            float hv = og * tanhfast(cn);
            h1cur[(ntile * 4 + eu) * 128 + rb + eb] = hv;
            h1ncur[(size_t)(rb + eb) * 512 + ntile * 4 + eu] = hv;
        }
        // no trailing syncthreads needed: next-iter xs writes are fenced by the
        // top-of-loop __syncthreads; zex/sq cross-step anti-deps are barrier-ordered
    }

    grid_barrier(bar);
    if (blk < 128 && w == 0)
        ypass(h1n + ((T_STEPS - 1) & 1) * 65536, wfT, bf, out, blk, T_STEPS - 1, lane);
}

// ---------------- launcher ----------------
extern "C" void kernel_launch(void* const* d_in, const int* in_sizes, int n_in,
                              void* d_out, int out_size, void* d_ws, size_t ws_size,
                              hipStream_t stream)
{
    const float* x     = (const float*)d_in[0];
    const float* w0    = (const float*)d_in[1];
    const float* u0    = (const float*)d_in[2];
    const float* b0    = (const float*)d_in[3];
    const float* gamma = (const float*)d_in[4];
    const float* beta  = (const float*)d_in[5];
    const float* w1    = (const float*)d_in[6];
    const float* u1    = (const float*)d_in[7];
    const float* b1    = (const float*)d_in[8];
    const float* wf    = (const float*)d_in[9];
    const float* bf    = (const float*)d_in[10];
    float* out = (float*)d_out;
    float* ws  = (float*)d_ws;

    hipLaunchKernelGGL(pack0_kernel, dim3(128 * 10), dim3(256), 0, stream, w0, u0, ws + OFF_BP0);
    hipLaunchKernelGGL(pack1_kernel, dim3(128 * 16), dim3(256), 0, stream, w1, u1, gamma, ws + OFF_BP1);
    hipLaunchKernelGGL(sums_kernel, dim3(8), dim3(256), 0, stream,
                       w1, gamma, beta, b0, b1, ws + OFF_S1P, ws + OFF_ZB1P, ws + OFF_B0P);
    hipLaunchKernelGGL(wft_kernel, dim3(14), dim3(512), 0, stream, wf, ws + OFF_WFT);
    hipLaunchKernelGGL(init_kernel, dim3(384), dim3(1024), 0, stream, ws);

    const float* xp  = x;
    const float* bfp = bf;
    float* wsp  = ws;
    float* outp = out;
    void* args[] = { (void*)&xp, (void*)&bfp, (void*)&wsp, (void*)&outp };
    hipLaunchCooperativeKernel((void*)lstm_main, dim3(256), dim3(512), args, 0, stream);
}